// Round 11
// baseline (319.914 us; speedup 1.0000x reference)
//
#include <hip/hip_runtime.h>

#define N_NODES 20000
#define N_EDGES 200000
#define DIM 128
#define T_STEPS 8
#define N_TILES (N_NODES / 16)          // 1250
#define SCAN_N (N_NODES + 1)            // 20001
#define SCAN_BLKS ((SCAN_N + 1023) / 1024)  // 20
#define LSTR 140   // LDS row stride in shorts: conflict-free b16 writes (verified r8/r10: SQ_LDS_BANK_CONFLICT=0)

typedef short short8 __attribute__((ext_vector_type(8)));
typedef float f32x4 __attribute__((ext_vector_type(4)));

static __device__ __forceinline__ unsigned short f2bf(float f) {
  union { float f; unsigned u; } v; v.f = f;
  unsigned r = v.u + 0x7fffu + ((v.u >> 16) & 1u);   // RNE
  return (unsigned short)(r >> 16);
}
static __device__ __forceinline__ float fast_tanh(float x) {
  float e = __expf(2.f * x);           // inf-safe: x>>0 -> 1, x<<0 -> -1
  return 1.f - 2.f / (e + 1.f);
}
static __device__ __forceinline__ float fast_sig(float x) {
  return 1.f / (1.f + __expf(-x));
}

// ---------------------------------------------------------------------------
// Repack the five 128x128 fp32 weight matrices (row-major W[k][n]) into bf16
// MFMA B-fragment order: pack[m][((nt*4+ks)*64+lane)*8+j] = bf16(W[k][n]),
// n = nt*16 + (lane&15), k = ks*32 + (lane>>4)*8 + j.
// Slots: 0=Wenc 1=Wz 2=Uz 3=Wh 4=Uh.
// ---------------------------------------------------------------------------
__global__ void repack5(const float* __restrict__ w0,
                        const float* __restrict__ w1,
                        const float* __restrict__ w2,
                        const float* __restrict__ w3,
                        const float* __restrict__ w4,
                        unsigned short* __restrict__ pack) {
  int i = blockIdx.x * blockDim.x + threadIdx.x;
  if (i >= 5 * 16384) return;
  int m = i >> 14, r = i & 16383;
  int j = r & 7, lane = (r >> 3) & 63, ks = (r >> 9) & 3, nt = (r >> 11) & 7;
  int n = nt * 16 + (lane & 15);
  int k = ks * 32 + (lane >> 4) * 8 + j;
  const float* w = (m == 0) ? w0 : (m == 1) ? w1 : (m == 2) ? w2
                 : (m == 3) ? w3 : w4;
  pack[i] = f2bf(w[k * DIM + n]);
}

// ------------------------- CSR build: bucket by dst ------------------------
__global__ void hist_k(const int* __restrict__ dst, int* __restrict__ counts) {
  int i = blockIdx.x * blockDim.x + threadIdx.x;
  if (i >= N_EDGES) return;
  atomicAdd(&counts[dst[i]], 1);
}

__global__ void scan1_k(const int* __restrict__ counts,
                        int* __restrict__ base, int* __restrict__ bsum) {
  __shared__ int ls[256];
  int tid = threadIdx.x;
  int i0 = blockIdx.x * 1024 + tid * 4;
  int v[4], ts = 0;
#pragma unroll
  for (int r = 0; r < 4; r++) {
    v[r] = (i0 + r < SCAN_N) ? counts[i0 + r] : 0;
    ts += v[r];
  }
  ls[tid] = ts; __syncthreads();
#pragma unroll
  for (int off = 1; off < 256; off <<= 1) {
    int x = (tid >= off) ? ls[tid - off] : 0;
    __syncthreads(); ls[tid] += x; __syncthreads();
  }
  int run = ls[tid] - ts;
  if (tid == 255) bsum[blockIdx.x] = ls[255];
#pragma unroll
  for (int r = 0; r < 4; r++) {
    if (i0 + r < SCAN_N) base[i0 + r] = run;
    run += v[r];
  }
}

__global__ void scan2_k(int* __restrict__ bsum) {
  __shared__ int ls[256];
  int tid = threadIdx.x;
  int v = (tid < SCAN_BLKS) ? bsum[tid] : 0;
  ls[tid] = v; __syncthreads();
#pragma unroll
  for (int off = 1; off < 256; off <<= 1) {
    int x = (tid >= off) ? ls[tid - off] : 0;
    __syncthreads(); ls[tid] += x; __syncthreads();
  }
  if (tid < SCAN_BLKS) bsum[tid] = ls[tid] - v;
}

__global__ void scan3_k(int* __restrict__ base, const int* __restrict__ bsum) {
  int i = blockIdx.x * blockDim.x + threadIdx.x;
  if (i < SCAN_N) base[i] += bsum[i >> 10];
}

// epack = src | rel<<15 | t<<23  (src<32768, rel<256, t<8)
__global__ void fill_k(const int* __restrict__ src, const int* __restrict__ dst,
                       const int* __restrict__ etype, const int* __restrict__ etime,
                       const float* __restrict__ ew,
                       const int* __restrict__ base, int* __restrict__ cursor,
                       unsigned* __restrict__ epack, float* __restrict__ sw) {
  int i = blockIdx.x * blockDim.x + threadIdx.x;
  if (i >= N_EDGES) return;
  int d = dst[i];
  int pos = base[d] + atomicAdd(&cursor[d], 1);
  epack[pos] = (unsigned)src[i] | ((unsigned)etype[i] << 15) | ((unsigned)etime[i] << 23);
  sw[pos] = ew[i];
}

// ---------------------------------------------------------------------------
// Gather: one wave per dst node; 8 per-t accumulator pairs in registers,
// predicated FMA on wave-uniform t. Writes all 8 agg[t][node] rows (bf16),
// including zeros -> no memset needed.
// ---------------------------------------------------------------------------
__global__ void gather_k(const int* __restrict__ base,
                         const unsigned* __restrict__ epack,
                         const float* __restrict__ sw,
                         const float* __restrict__ nemb,
                         const float* __restrict__ remb,
                         unsigned short* __restrict__ aggb) {
  int lane = threadIdx.x & 63;
  int node = (blockIdx.x * blockDim.x + threadIdx.x) >> 6;   // 0..N_NODES-1
  int s0 = base[node], s1 = base[node + 1];
  float ax[T_STEPS], ay[T_STEPS];
#pragma unroll
  for (int tt = 0; tt < T_STEPS; tt++) { ax[tt] = 0.f; ay[tt] = 0.f; }
  for (int i = s0; i < s1; i++) {
    unsigned u = epack[i];
    float w = sw[i];
    int s = u & 0x7fff, rt = (u >> 15) & 0xff, t = u >> 23;
    float2 sv = ((const float2*)(nemb + (size_t)s * DIM))[lane];
    float2 rv = ((const float2*)(remb + (size_t)rt * DIM))[lane];
    float m0 = sv.x * rv.x * w;
    float m1 = sv.y * rv.y * w;
#pragma unroll
    for (int tt = 0; tt < T_STEPS; tt++) {
      ax[tt] += (t == tt) ? m0 : 0.f;
      ay[tt] += (t == tt) ? m1 : 0.f;
    }
  }
#pragma unroll
  for (int tt = 0; tt < T_STEPS; tt++) {
    ushort2 o; o.x = f2bf(ax[tt]); o.y = f2bf(ay[tt]);
    ((ushort2*)(aggb + ((size_t)tt * N_NODES + node) * DIM))[lane] = o;
  }
}

// ---------------------------------------------------------------------------
// Fused encoder + GRU recurrence, gate weights in LDS.
// One block per 16-row tile (grid 1250), 8 waves; wave nt owns one 16-column
// tile. r7-r10 established: registers can't pin the weights (allocator turns
// it into AGPR copy storms, r9) and per-step L2 reloads are the floor (~37 µs
// of L2 BW + latency, r7/r8); TPB>1 starves the grid (r10). So the 4 gate
// matrices (128 KB, B-frag order) are staged ONCE into LDS per block; with
// the H/S double buffer (17.9 KB) total LDS = 149 KB -> 1 block/CU.
// The encoder (state-independent) is hoisted out of the serial loop: all 8
// steps' H C-frags are computed up front (32 MFMAs, ILP-overlapped, all L2
// traffic off the critical path) and carried as bf16 in registers.
// Per step: write H/S to LDS (stride LSTR, conflict-free), ONE barrier,
// 24 ds_read_b128 + 16 MFMAs + gate VALU -> pure LDS/MFMA loop.
// MFMA 16x16x32_bf16 layouts (HW-verified): A: m=lane&15,k=quad*8+j;
// B: n=lane&15,k=quad*8+j;  C/D: col=lane&15, row=quad*4+reg.
// Dbuf WAR safety: buffer X writes at t+2 are after barrier(t+1) which is
// after all X reads at t.
// ---------------------------------------------------------------------------
__launch_bounds__(512)
__global__ void fused_recur(const unsigned short* __restrict__ aggb,
                            const unsigned short* __restrict__ pack,
                            const float* __restrict__ bz,
                            const float* __restrict__ bh,
                            float* __restrict__ out) {
  __shared__ unsigned short wLDS[4 * 16384];     // Wz,Uz,Wh,Uh frags (128 KB)
  __shared__ unsigned short Hb[2][16 * LSTR];    // 8.96 KB
  __shared__ unsigned short Sb[2][16 * LSTR];    // 8.96 KB
  int tid = threadIdx.x;
  int lane = tid & 63;
  int nt = tid >> 6;                // wave id = column tile, 0..7
  int tile = blockIdx.x;
  int q = lane >> 4, l15 = lane & 15;
  int row0 = tile * 16;

  // ---- stage gate weights (pack slots 1..4) into LDS: 8192 short8 copies ----
  {
    const short8* sp = (const short8*)(pack + 16384);
    short8* dp = (short8*)wLDS;
    for (int i = tid; i < 8192; i += 512) dp[i] = sp[i];
  }

  // ---- precompute H for ALL steps (state-independent, full ILP) ----
  f32x4 acch[T_STEPS];
#pragma unroll
  for (int t = 0; t < T_STEPS; t++) acch[t] = (f32x4){0.f, 0.f, 0.f, 0.f};
#pragma unroll
  for (int ks = 0; ks < 4; ks++) {
    short8 wenc = *(const short8*)(pack + ((nt * 4 + ks) * 64 + lane) * 8);
#pragma unroll
    for (int t = 0; t < T_STEPS; t++) {
      short8 aA = *(const short8*)(aggb +
          ((size_t)t * N_NODES + row0 + l15) * DIM + ks * 32 + q * 8);
      acch[t] = __builtin_amdgcn_mfma_f32_16x16x32_bf16(aA, wenc, acch[t], 0, 0, 0);
    }
  }
  unsigned short hs[T_STEPS][4];
#pragma unroll
  for (int t = 0; t < T_STEPS; t++)
#pragma unroll
    for (int r = 0; r < 4; r++)
      hs[t][r] = f2bf(fast_tanh(acch[t][r]));

  float bzv = bz[nt * 16 + l15];
  float bhv = bh[nt * 16 + l15];

  __syncthreads();   // weights staged before first use

  f32x4 stC = (f32x4){0.f, 0.f, 0.f, 0.f};

  for (int t = 0; t < T_STEPS; t++) {
    unsigned short* hB = Hb[t & 1];
    unsigned short* sB = Sb[t & 1];
#pragma unroll
    for (int r = 0; r < 4; r++) {
      hB[(q * 4 + r) * LSTR + nt * 16 + l15] = hs[t][r];
      sB[(q * 4 + r) * LSTR + nt * 16 + l15] = f2bf(stC[r]);
    }
    __syncthreads();

    short8 hA[4], sA[4];
#pragma unroll
    for (int ks = 0; ks < 4; ks++) {
      int lo = l15 * LSTR + ks * 32 + q * 8;
      hA[ks] = *(const short8*)&hB[lo];
      sA[ks] = *(const short8*)&sB[lo];
    }

    f32x4 accz = (f32x4){bzv, bzv, bzv, bzv};
    f32x4 accc = (f32x4){bhv, bhv, bhv, bhv};
#pragma unroll
    for (int ks = 0; ks < 4; ks++) {
      int fo = ((nt * 4 + ks) * 64 + lane) * 8;
      short8 wz = *(const short8*)&wLDS[0 * 16384 + fo];
      short8 uz = *(const short8*)&wLDS[1 * 16384 + fo];
      short8 wh = *(const short8*)&wLDS[2 * 16384 + fo];
      short8 uh = *(const short8*)&wLDS[3 * 16384 + fo];
      accz = __builtin_amdgcn_mfma_f32_16x16x32_bf16(hA[ks], wz, accz, 0, 0, 0);
      accz = __builtin_amdgcn_mfma_f32_16x16x32_bf16(sA[ks], uz, accz, 0, 0, 0);
      accc = __builtin_amdgcn_mfma_f32_16x16x32_bf16(hA[ks], wh, accc, 0, 0, 0);
      accc = __builtin_amdgcn_mfma_f32_16x16x32_bf16(sA[ks], uh, accc, 0, 0, 0);
    }
#pragma unroll
    for (int r = 0; r < 4; r++) {
      float z = fast_sig(accz[r]);
      float c = fast_tanh(accc[r]);
      stC[r] = (1.f - z) * stC[r] + z * c;
    }
  }

  // final state -> out (fp32, C-layout positions)
#pragma unroll
  for (int r = 0; r < 4; r++)
    out[(size_t)(row0 + q * 4 + r) * DIM + nt * 16 + l15] = stC[r];
}

extern "C" void kernel_launch(void* const* d_in, const int* in_sizes, int n_in,
                              void* d_out, int out_size, void* d_ws, size_t ws_size,
                              hipStream_t stream) {
  const int* eidx  = (const int*)d_in[0];
  const int* src   = eidx;
  const int* dst   = eidx + N_EDGES;
  const int* etype = (const int*)d_in[1];
  const int* etime = (const int*)d_in[2];
  const float* ew   = (const float*)d_in[3];
  const float* nemb = (const float*)d_in[4];
  const float* remb = (const float*)d_in[5];
  const float* Wenc = (const float*)d_in[6];
  const float* Wz   = (const float*)d_in[7];
  const float* Uz   = (const float*)d_in[8];
  const float* Wh   = (const float*)d_in[9];
  const float* Uh   = (const float*)d_in[10];
  const float* bz   = (const float*)d_in[11];
  const float* bh   = (const float*)d_in[12];
  // d_in[13] = num_times (constant 8 for this problem's fixed shapes)

  // ws layout
  unsigned short* aggb = (unsigned short*)d_ws;                    // 41 MB
  int* counts = (int*)(aggb + (size_t)T_STEPS * N_NODES * DIM);    // SCAN_N
  int* cursor = counts + SCAN_N;                                   // N_NODES
  int* bsum   = cursor + N_NODES;                                  // 64
  int* base   = bsum + 64;                                         // SCAN_N
  unsigned* epack = (unsigned*)(base + SCAN_N);                    // E
  float* sw   = (float*)(epack + N_EDGES);                         // E
  // 64B-align pack for clean b128 loads
  unsigned short* pack = (unsigned short*)(((uintptr_t)(sw + N_EDGES) + 63) & ~(uintptr_t)63);
  float* outp = (float*)d_out;

  hipMemsetAsync(counts, 0, (size_t)(SCAN_N + N_NODES) * sizeof(int), stream);
  repack5<<<(5 * 16384 + 255) / 256, 256, 0, stream>>>(Wenc, Wz, Uz, Wh, Uh, pack);
  hist_k<<<(N_EDGES + 255) / 256, 256, 0, stream>>>(dst, counts);
  scan1_k<<<SCAN_BLKS, 256, 0, stream>>>(counts, base, bsum);
  scan2_k<<<1, 256, 0, stream>>>(bsum);
  scan3_k<<<(SCAN_N + 255) / 256, 256, 0, stream>>>(base, bsum);
  fill_k<<<(N_EDGES + 255) / 256, 256, 0, stream>>>(src, dst, etype, etime, ew,
                                                    base, cursor, epack, sw);
  gather_k<<<N_NODES / 4, 256, 0, stream>>>(base, epack, sw, nemb, remb, aggb);
  fused_recur<<<N_TILES, 512, 0, stream>>>(aggb, pack, bz, bh, outp);
}

// Round 12
// 258.129 us; speedup vs baseline: 1.2394x; 1.2394x over previous
//
#include <hip/hip_runtime.h>

#define N_NODES 20000
#define N_EDGES 200000
#define DIM 128
#define T_STEPS 8
#define N_TILES (N_NODES / 16)          // 1250
#define NB (N_NODES * T_STEPS)          // 160000 (dst,t) buckets
#define SCAN_N (NB + 1)                 // 160001
#define SCAN_BLKS ((SCAN_N + 1023) / 1024)  // 157
#define LSTR 140   // LDS row stride in shorts: conflict-free b16 writes (verified r8/r10/r11: SQ_LDS_BANK_CONFLICT=0)

typedef short short8 __attribute__((ext_vector_type(8)));
typedef float f32x4 __attribute__((ext_vector_type(4)));

static __device__ __forceinline__ unsigned short f2bf(float f) {
  union { float f; unsigned u; } v; v.f = f;
  unsigned r = v.u + 0x7fffu + ((v.u >> 16) & 1u);   // RNE
  return (unsigned short)(r >> 16);
}
static __device__ __forceinline__ float fast_tanh(float x) {
  float e = __expf(2.f * x);           // inf-safe: x>>0 -> 1, x<<0 -> -1
  return 1.f - 2.f / (e + 1.f);
}
static __device__ __forceinline__ float fast_sig(float x) {
  return 1.f / (1.f + __expf(-x));
}

// ---------------------------------------------------------------------------
// Repack the five 128x128 fp32 weight matrices (row-major W[k][n]) into bf16
// MFMA B-fragment order: pack[m][((nt*4+ks)*64+lane)*8+j] = bf16(W[k][n]),
// n = nt*16 + (lane&15), k = ks*32 + (lane>>4)*8 + j.
// Slots: 0=Wenc 1=Wz 2=Uz 3=Wh 4=Uh.
// ---------------------------------------------------------------------------
__global__ void repack5(const float* __restrict__ w0,
                        const float* __restrict__ w1,
                        const float* __restrict__ w2,
                        const float* __restrict__ w3,
                        const float* __restrict__ w4,
                        unsigned short* __restrict__ pack) {
  int i = blockIdx.x * blockDim.x + threadIdx.x;
  if (i >= 5 * 16384) return;
  int m = i >> 14, r = i & 16383;
  int j = r & 7, lane = (r >> 3) & 63, ks = (r >> 9) & 3, nt = (r >> 11) & 7;
  int n = nt * 16 + (lane & 15);
  int k = ks * 32 + (lane >> 4) * 8 + j;
  const float* w = (m == 0) ? w0 : (m == 1) ? w1 : (m == 2) ? w2
                 : (m == 3) ? w3 : w4;
  pack[i] = f2bf(w[k * DIM + n]);
}

// ---------------- CSR build: bucket by key = dst*8 + t ---------------------
__global__ void hist_k(const int* __restrict__ dst, const int* __restrict__ etime,
                       int* __restrict__ counts) {
  int i = blockIdx.x * blockDim.x + threadIdx.x;
  if (i >= N_EDGES) return;
  atomicAdd(&counts[dst[i] * T_STEPS + etime[i]], 1);
}

__global__ void scan1_k(const int* __restrict__ counts,
                        int* __restrict__ base, int* __restrict__ bsum) {
  __shared__ int ls[256];
  int tid = threadIdx.x;
  int i0 = blockIdx.x * 1024 + tid * 4;
  int v[4], ts = 0;
#pragma unroll
  for (int r = 0; r < 4; r++) {
    v[r] = (i0 + r < SCAN_N) ? counts[i0 + r] : 0;
    ts += v[r];
  }
  ls[tid] = ts; __syncthreads();
#pragma unroll
  for (int off = 1; off < 256; off <<= 1) {
    int x = (tid >= off) ? ls[tid - off] : 0;
    __syncthreads(); ls[tid] += x; __syncthreads();
  }
  int run = ls[tid] - ts;
  if (tid == 255) bsum[blockIdx.x] = ls[255];
#pragma unroll
  for (int r = 0; r < 4; r++) {
    if (i0 + r < SCAN_N) base[i0 + r] = run;
    run += v[r];
  }
}

__global__ void scan2_k(int* __restrict__ bsum) {
  __shared__ int ls[256];
  int tid = threadIdx.x;
  int v = (tid < SCAN_BLKS) ? bsum[tid] : 0;
  ls[tid] = v; __syncthreads();
#pragma unroll
  for (int off = 1; off < 256; off <<= 1) {
    int x = (tid >= off) ? ls[tid - off] : 0;
    __syncthreads(); ls[tid] += x; __syncthreads();
  }
  if (tid < SCAN_BLKS) bsum[tid] = ls[tid] - v;
}

__global__ void scan3_k(int* __restrict__ base, const int* __restrict__ bsum) {
  int i = blockIdx.x * blockDim.x + threadIdx.x;
  if (i < SCAN_N) base[i] += bsum[i >> 10];
}

// epack = src | rel<<15 | t<<23  (src<32768, rel<256, t<8)
__global__ void fill_k(const int* __restrict__ src, const int* __restrict__ dst,
                       const int* __restrict__ etype, const int* __restrict__ etime,
                       const float* __restrict__ ew,
                       const int* __restrict__ base, int* __restrict__ cursor,
                       unsigned* __restrict__ epack, float* __restrict__ sw) {
  int i = blockIdx.x * blockDim.x + threadIdx.x;
  if (i >= N_EDGES) return;
  int key = dst[i] * T_STEPS + etime[i];
  int pos = base[key] + atomicAdd(&cursor[key], 1);
  epack[pos] = (unsigned)src[i] | ((unsigned)etype[i] << 15) | ((unsigned)etime[i] << 23);
  sw[pos] = ew[i];
}

// ---------------------------------------------------------------------------
// Gather, run-flush style: one wave per dst node; edges arrive t-sorted
// (CSR keyed (dst,t)), so the wave keeps ONE running (ax,ay) pair and flushes
// it to agg[t][node] when t changes — 2 FMAs + a wave-uniform compare per
// edge (r7's t-predicated version burned 32 VALU ops/edge: 16x inflation).
// Empty (t,node) rows are zero-filled via an 8-bit written-mask (no memset).
// ---------------------------------------------------------------------------
__global__ void gather_k(const int* __restrict__ base,
                         const unsigned* __restrict__ epack,
                         const float* __restrict__ sw,
                         const float* __restrict__ nemb,
                         const float* __restrict__ remb,
                         unsigned short* __restrict__ aggb) {
  int lane = threadIdx.x & 63;
  int node = (blockIdx.x * blockDim.x + threadIdx.x) >> 6;   // 0..N_NODES-1
  int s0 = base[node * T_STEPS], s1 = base[node * T_STEPS + T_STEPS];
  float ax = 0.f, ay = 0.f;
  int cur = -1;
  unsigned wmask = 0;
  for (int i = s0; i < s1; i++) {
    unsigned u = epack[i];
    float w = sw[i];
    int t = (int)(u >> 23);
    if (t != cur) {                       // wave-uniform branch
      if (cur >= 0) {
        ushort2 o; o.x = f2bf(ax); o.y = f2bf(ay);
        ((ushort2*)(aggb + ((size_t)cur * N_NODES + node) * DIM))[lane] = o;
        wmask |= 1u << cur;
      }
      ax = 0.f; ay = 0.f; cur = t;
    }
    int s = u & 0x7fff, rt = (u >> 15) & 0xff;
    float2 sv = ((const float2*)(nemb + (size_t)s * DIM))[lane];
    float2 rv = ((const float2*)(remb + (size_t)rt * DIM))[lane];
    ax += sv.x * rv.x * w;
    ay += sv.y * rv.y * w;
  }
  if (cur >= 0) {
    ushort2 o; o.x = f2bf(ax); o.y = f2bf(ay);
    ((ushort2*)(aggb + ((size_t)cur * N_NODES + node) * DIM))[lane] = o;
    wmask |= 1u << cur;
  }
  ushort2 z; z.x = 0; z.y = 0;
#pragma unroll
  for (int t = 0; t < T_STEPS; t++)
    if (!((wmask >> t) & 1))
      ((ushort2*)(aggb + ((size_t)t * N_NODES + node) * DIM))[lane] = z;
}

// ---------------------------------------------------------------------------
// Fused encoder + GRU recurrence — r7's best-measured structure (70 µs),
// with the verified conflict-free LDS stride (LSTR=140; r7 ran 136 and paid
// 2.56M conflict cycles). One block per 16-row tile (grid 1250), 8 waves;
// wave nt owns one 16-column tile. Weights stream from L2 each step (r9's
// register pinning -> AGPR copy storms; r10 TPB=4 and r11 LDS staging ->
// occupancy collapse; occupancy wins). Per step t:
//   H = fast_tanh(agg[t] @ Wenc[:,nt])  (4 MFMAs),
//   H,S -> dbuf LDS, ONE barrier, A-frag reads,
//   zpre = bz + H@Wz + S@Uz ; cpre = bh + H@Wh + S@Uh  (16 MFMAs),
//   S = (1-sig)*S + sig*fast_tanh(cpre)
// MFMA 16x16x32_bf16 layouts (HW-verified): A: m=lane&15,k=quad*8+j;
// B: n=lane&15,k=quad*8+j;  C/D: col=lane&15, row=quad*4+reg.
// Dbuf WAR safety: buffer X writes at t+2 are after barrier(t+1) which is
// after all X reads at t.
// ---------------------------------------------------------------------------
__launch_bounds__(512)
__global__ void fused_recur(const unsigned short* __restrict__ aggb,
                            const unsigned short* __restrict__ pack,
                            const float* __restrict__ bz,
                            const float* __restrict__ bh,
                            float* __restrict__ out) {
  __shared__ unsigned short Hb[2][16 * LSTR];
  __shared__ unsigned short Sb[2][16 * LSTR];
  int lane = threadIdx.x & 63;
  int nt = threadIdx.x >> 6;        // wave id = column tile, 0..7
  int tile = blockIdx.x;
  int q = lane >> 4, l15 = lane & 15;
  int row0 = tile * 16;

  float bzv = bz[nt * 16 + l15];
  float bhv = bh[nt * 16 + l15];

  f32x4 stC = (f32x4){0.f, 0.f, 0.f, 0.f};

  for (int t = 0; t < T_STEPS; t++) {
    // ---- encoder slice for this step (state-independent) ----
    f32x4 acch = (f32x4){0.f, 0.f, 0.f, 0.f};
#pragma unroll
    for (int ks = 0; ks < 4; ks++) {
      short8 wenc = *(const short8*)(pack + ((nt * 4 + ks) * 64 + lane) * 8);
      short8 aA = *(const short8*)(aggb +
          ((size_t)t * N_NODES + row0 + l15) * DIM + ks * 32 + q * 8);
      acch = __builtin_amdgcn_mfma_f32_16x16x32_bf16(aA, wenc, acch, 0, 0, 0);
    }
    unsigned short* hB = Hb[t & 1];
    unsigned short* sB = Sb[t & 1];
#pragma unroll
    for (int r = 0; r < 4; r++) {
      hB[(q * 4 + r) * LSTR + nt * 16 + l15] = f2bf(fast_tanh(acch[r]));
      sB[(q * 4 + r) * LSTR + nt * 16 + l15] = f2bf(stC[r]);
    }
    __syncthreads();

    short8 hA[4], sA[4];
#pragma unroll
    for (int ks = 0; ks < 4; ks++) {
      int lo = l15 * LSTR + ks * 32 + q * 8;
      hA[ks] = *(const short8*)&hB[lo];
      sA[ks] = *(const short8*)&sB[lo];
    }

    f32x4 accz = (f32x4){bzv, bzv, bzv, bzv};
    f32x4 accc = (f32x4){bhv, bhv, bhv, bhv};
#pragma unroll
    for (int ks = 0; ks < 4; ks++) {
      int fo = ((nt * 4 + ks) * 64 + lane) * 8;
      short8 wz = *(const short8*)(pack + 16384 * 1 + fo);
      short8 uz = *(const short8*)(pack + 16384 * 2 + fo);
      short8 wh = *(const short8*)(pack + 16384 * 3 + fo);
      short8 uh = *(const short8*)(pack + 16384 * 4 + fo);
      accz = __builtin_amdgcn_mfma_f32_16x16x32_bf16(hA[ks], wz, accz, 0, 0, 0);
      accz = __builtin_amdgcn_mfma_f32_16x16x32_bf16(sA[ks], uz, accz, 0, 0, 0);
      accc = __builtin_amdgcn_mfma_f32_16x16x32_bf16(hA[ks], wh, accc, 0, 0, 0);
      accc = __builtin_amdgcn_mfma_f32_16x16x32_bf16(sA[ks], uh, accc, 0, 0, 0);
    }
#pragma unroll
    for (int r = 0; r < 4; r++) {
      float z = fast_sig(accz[r]);
      float c = fast_tanh(accc[r]);
      stC[r] = (1.f - z) * stC[r] + z * c;
    }
  }

  // final state -> out (fp32, C-layout positions)
#pragma unroll
  for (int r = 0; r < 4; r++)
    out[(size_t)(row0 + q * 4 + r) * DIM + nt * 16 + l15] = stC[r];
}

extern "C" void kernel_launch(void* const* d_in, const int* in_sizes, int n_in,
                              void* d_out, int out_size, void* d_ws, size_t ws_size,
                              hipStream_t stream) {
  const int* eidx  = (const int*)d_in[0];
  const int* src   = eidx;
  const int* dst   = eidx + N_EDGES;
  const int* etype = (const int*)d_in[1];
  const int* etime = (const int*)d_in[2];
  const float* ew   = (const float*)d_in[3];
  const float* nemb = (const float*)d_in[4];
  const float* remb = (const float*)d_in[5];
  const float* Wenc = (const float*)d_in[6];
  const float* Wz   = (const float*)d_in[7];
  const float* Uz   = (const float*)d_in[8];
  const float* Wh   = (const float*)d_in[9];
  const float* Uh   = (const float*)d_in[10];
  const float* bz   = (const float*)d_in[11];
  const float* bh   = (const float*)d_in[12];
  // d_in[13] = num_times (constant 8 for this problem's fixed shapes)

  // ws layout
  unsigned short* aggb = (unsigned short*)d_ws;                    // 41 MB
  int* counts = (int*)(aggb + (size_t)T_STEPS * N_NODES * DIM);    // SCAN_N
  int* cursor = counts + SCAN_N;                                   // NB
  int* bsum   = cursor + NB;                                       // 256
  int* base   = bsum + 256;                                        // SCAN_N
  unsigned* epack = (unsigned*)(base + SCAN_N);                    // E
  float* sw   = (float*)(epack + N_EDGES);                         // E
  // 64B-align pack for clean b128 loads
  unsigned short* pack = (unsigned short*)(((uintptr_t)(sw + N_EDGES) + 63) & ~(uintptr_t)63);
  float* outp = (float*)d_out;

  hipMemsetAsync(counts, 0, (size_t)(SCAN_N + NB) * sizeof(int), stream);
  repack5<<<(5 * 16384 + 255) / 256, 256, 0, stream>>>(Wenc, Wz, Uz, Wh, Uh, pack);
  hist_k<<<(N_EDGES + 255) / 256, 256, 0, stream>>>(dst, etime, counts);
  scan1_k<<<SCAN_BLKS, 256, 0, stream>>>(counts, base, bsum);
  scan2_k<<<1, 256, 0, stream>>>(bsum);
  scan3_k<<<(SCAN_N + 255) / 256, 256, 0, stream>>>(base, bsum);
  fill_k<<<(N_EDGES + 255) / 256, 256, 0, stream>>>(src, dst, etype, etime, ew,
                                                    base, cursor, epack, sw);
  gather_k<<<N_NODES / 4, 256, 0, stream>>>(base, epack, sw, nemb, remb, aggb);
  fused_recur<<<N_TILES, 512, 0, stream>>>(aggb, pack, bz, bh, outp);
}